// Round 1
// baseline (2694.831 us; speedup 1.0000x reference)
//
#include <hip/hip_runtime.h>
#include <hip/hip_bf16.h>

#define T_TOKENS 4096
#define DM 1024
#define DF 4096
#define NE 8

typedef float f32x4 __attribute__((ext_vector_type(4)));
typedef short bf16x8 __attribute__((ext_vector_type(8)));

__device__ inline unsigned short f2bf(float f) {
    union { float f; unsigned int u; } v; v.f = f;
    unsigned int r = v.u + 0x7fffu + ((v.u >> 16) & 1u);
    return (unsigned short)(r >> 16);
}

// ---------------- gating: logits -> top2 (softmax is monotone, skip it) ----------------
__global__ __launch_bounds__(256) void gate_kernel(
    const float* __restrict__ x, const float* __restrict__ Wg, const float* __restrict__ bg,
    int* __restrict__ counts, int* __restrict__ topk)
{
    int wave = threadIdx.x >> 6;
    int lane = threadIdx.x & 63;
    int t = blockIdx.x * 4 + wave;
    float acc[NE];
#pragma unroll
    for (int e = 0; e < NE; e++) acc[e] = 0.f;
    const float* xr = x + (size_t)t * DM;
#pragma unroll
    for (int i = 0; i < DM / 64; i++) {
        int d = lane + i * 64;
        float xv = xr[d];
        const float4* wg = (const float4*)(Wg + d * NE);
        float4 w0 = wg[0], w1 = wg[1];
        acc[0] += xv * w0.x; acc[1] += xv * w0.y; acc[2] += xv * w0.z; acc[3] += xv * w0.w;
        acc[4] += xv * w1.x; acc[5] += xv * w1.y; acc[6] += xv * w1.z; acc[7] += xv * w1.w;
    }
#pragma unroll
    for (int e = 0; e < NE; e++) {
#pragma unroll
        for (int off = 32; off > 0; off >>= 1)
            acc[e] += __shfl_down(acc[e], off);
    }
    if (lane == 0) {
        float lg[NE];
#pragma unroll
        for (int e = 0; e < NE; e++) lg[e] = acc[e] + bg[e];
        int b1i = 0; float b1v = lg[0];
        for (int e = 1; e < NE; e++) if (lg[e] > b1v) { b1v = lg[e]; b1i = e; }
        int b2i = -1; float b2v = -1e30f;
        for (int e = 0; e < NE; e++) {
            if (e == b1i) continue;
            if (b2i < 0 || lg[e] > b2v) { b2v = lg[e]; b2i = e; }
        }
        topk[t * 2 + 0] = b1i;
        topk[t * 2 + 1] = b2i;
        atomicAdd(&counts[b1i], 1);
        atomicAdd(&counts[b2i], 1);
    }
}

// ---------------- build per-expert token lists ----------------
__global__ __launch_bounds__(256) void scatter_kernel(
    const int* __restrict__ counts, const int* __restrict__ topk,
    int* __restrict__ offsets, int* __restrict__ list)
{
    __shared__ int offs[NE + 1];
    __shared__ int cur[NE];
    if (threadIdx.x == 0) {
        int s = 0;
        for (int e = 0; e < NE; e++) { offs[e] = s; offsets[e] = s; s += counts[e]; }
        offs[NE] = s; offsets[NE] = s;
    }
    if (threadIdx.x < NE) cur[threadIdx.x] = 0;
    __syncthreads();
    for (int i = threadIdx.x; i < T_TOKENS * 2; i += 256) {
        int e = topk[i];
        int pos = atomicAdd(&cur[e], 1);
        list[offs[e] + pos] = i >> 1;
    }
}

// ---------------- GEMM1: H = relu(X_gathered @ W1[e] + b1[e]), H in bf16 ----------------
__global__ __launch_bounds__(256) void gemm1_kernel(
    const float* __restrict__ x, const float* __restrict__ W1, const float* __restrict__ b1,
    const int* __restrict__ counts, const int* __restrict__ offsets, const int* __restrict__ list,
    unsigned short* __restrict__ H, int e)
{
    const int count = counts[e];
    const int row0 = blockIdx.x * 64;
    if (row0 >= count) return;
    const int n0 = blockIdx.y * 64;
    const float* W = W1 + (size_t)e * DM * DF;
    const float* bias = b1 + e * DF;
    const int* lst = list + offsets[e];

    __shared__ unsigned short Asm[64][40];
    __shared__ unsigned short Bsm[64][40];  // transposed: [n][k]

    const int tid = threadIdx.x;
    const int wave = tid >> 6, lane = tid & 63;
    const int quad = lane >> 4, l16 = lane & 15;

    const int ar = tid >> 2;
    const int ac = (tid & 3) * 8;
    const int grA = row0 + ar;
    const int tokA = (grA < count) ? lst[grA] : -1;
    const float* xr = (tokA >= 0) ? (x + (size_t)tokA * DM) : x;

    const int bk = tid >> 3;
    const int bn = (tid & 7) * 8;

    f32x4 acc[4];
#pragma unroll
    for (int i = 0; i < 4; i++) acc[i] = (f32x4){0.f, 0.f, 0.f, 0.f};

    for (int kk = 0; kk < DM; kk += 32) {
        unsigned short av[8];
        if (tokA >= 0) {
            const float4* p = (const float4*)(xr + kk + ac);
            float4 v0 = p[0], v1 = p[1];
            av[0] = f2bf(v0.x); av[1] = f2bf(v0.y); av[2] = f2bf(v0.z); av[3] = f2bf(v0.w);
            av[4] = f2bf(v1.x); av[5] = f2bf(v1.y); av[6] = f2bf(v1.z); av[7] = f2bf(v1.w);
        } else {
#pragma unroll
            for (int j = 0; j < 8; j++) av[j] = 0;
        }
        *(uint4*)&Asm[ar][ac] = *(const uint4*)av;

        const float4* q = (const float4*)(W + (size_t)(kk + bk) * DF + n0 + bn);
        float4 w0 = q[0], w1 = q[1];
        Bsm[bn + 0][bk] = f2bf(w0.x);
        Bsm[bn + 1][bk] = f2bf(w0.y);
        Bsm[bn + 2][bk] = f2bf(w0.z);
        Bsm[bn + 3][bk] = f2bf(w0.w);
        Bsm[bn + 4][bk] = f2bf(w1.x);
        Bsm[bn + 5][bk] = f2bf(w1.y);
        Bsm[bn + 6][bk] = f2bf(w1.z);
        Bsm[bn + 7][bk] = f2bf(w1.w);
        __syncthreads();

        bf16x8 afrag = *(const bf16x8*)&Asm[wave * 16 + l16][quad * 8];
#pragma unroll
        for (int nt = 0; nt < 4; nt++) {
            bf16x8 bfrag = *(const bf16x8*)&Bsm[nt * 16 + l16][quad * 8];
            acc[nt] = __builtin_amdgcn_mfma_f32_16x16x32_bf16(afrag, bfrag, acc[nt], 0, 0, 0);
        }
        __syncthreads();
    }

#pragma unroll
    for (int nt = 0; nt < 4; nt++) {
#pragma unroll
        for (int r = 0; r < 4; r++) {
            int m = wave * 16 + quad * 4 + r;
            int gr = row0 + m;
            if (gr < count) {
                int n = n0 + nt * 16 + l16;
                float v = acc[nt][r] + bias[n];
                v = fmaxf(v, 0.f);
                H[(size_t)gr * DF + n] = f2bf(v);
            }
        }
    }
}

// ---------------- GEMM2: out[token] += H @ W2[e] + b2[e] ----------------
__global__ __launch_bounds__(256) void gemm2_kernel(
    const unsigned short* __restrict__ H, const float* __restrict__ W2, const float* __restrict__ b2,
    const int* __restrict__ counts, const int* __restrict__ offsets, const int* __restrict__ list,
    float* __restrict__ out, int e)
{
    const int count = counts[e];
    const int row0 = blockIdx.x * 64;
    if (row0 >= count) return;
    const int n0 = blockIdx.y * 64;
    const float* W = W2 + (size_t)e * DF * DM;
    const float* bias = b2 + e * DM;
    const int* lst = list + offsets[e];

    __shared__ unsigned short Asm[64][40];
    __shared__ unsigned short Bsm[64][40];  // transposed: [n][k]

    const int tid = threadIdx.x;
    const int wave = tid >> 6, lane = tid & 63;
    const int quad = lane >> 4, l16 = lane & 15;

    const int ar = tid >> 2;
    const int ac = (tid & 3) * 8;
    const int grA = row0 + ar;
    const bool okA = (grA < count);

    const int bk = tid >> 3;
    const int bn = (tid & 7) * 8;

    f32x4 acc[4];
#pragma unroll
    for (int i = 0; i < 4; i++) acc[i] = (f32x4){0.f, 0.f, 0.f, 0.f};

    for (int kk = 0; kk < DF; kk += 32) {
        uint4 v;
        if (okA) v = *(const uint4*)(H + (size_t)grA * DF + kk + ac);
        else     v = make_uint4(0u, 0u, 0u, 0u);
        *(uint4*)&Asm[ar][ac] = v;

        const float4* q = (const float4*)(W + (size_t)(kk + bk) * DM + n0 + bn);
        float4 w0 = q[0], w1 = q[1];
        Bsm[bn + 0][bk] = f2bf(w0.x);
        Bsm[bn + 1][bk] = f2bf(w0.y);
        Bsm[bn + 2][bk] = f2bf(w0.z);
        Bsm[bn + 3][bk] = f2bf(w0.w);
        Bsm[bn + 4][bk] = f2bf(w1.x);
        Bsm[bn + 5][bk] = f2bf(w1.y);
        Bsm[bn + 6][bk] = f2bf(w1.z);
        Bsm[bn + 7][bk] = f2bf(w1.w);
        __syncthreads();

        bf16x8 afrag = *(const bf16x8*)&Asm[wave * 16 + l16][quad * 8];
#pragma unroll
        for (int nt = 0; nt < 4; nt++) {
            bf16x8 bfrag = *(const bf16x8*)&Bsm[nt * 16 + l16][quad * 8];
            acc[nt] = __builtin_amdgcn_mfma_f32_16x16x32_bf16(afrag, bfrag, acc[nt], 0, 0, 0);
        }
        __syncthreads();
    }

#pragma unroll
    for (int nt = 0; nt < 4; nt++) {
#pragma unroll
        for (int r = 0; r < 4; r++) {
            int m = wave * 16 + quad * 4 + r;
            int gr = row0 + m;
            if (gr < count) {
                int tk = lst[gr];
                int n = n0 + nt * 16 + l16;
                float v = acc[nt][r] + bias[n];
                out[(size_t)tk * DM + n] += v;  // safe: unique (tk,n) per kernel; kernels serialize on stream
            }
        }
    }
}

extern "C" void kernel_launch(void* const* d_in, const int* in_sizes, int n_in,
                              void* d_out, int out_size, void* d_ws, size_t ws_size,
                              hipStream_t stream)
{
    const float* x  = (const float*)d_in[0];
    const float* Wg = (const float*)d_in[1];
    const float* bg = (const float*)d_in[2];
    const float* W1 = (const float*)d_in[3];
    const float* b1 = (const float*)d_in[4];
    const float* W2 = (const float*)d_in[5];
    const float* b2 = (const float*)d_in[6];
    float* out = (float*)d_out;

    int* wsi = (int*)d_ws;
    int* counts  = wsi;            // 8 ints
    int* offsets = wsi + 8;        // 9 ints
    int* topk    = wsi + 32;       // 8192 ints
    int* list    = wsi + 32 + 8192;// 8192 ints
    unsigned short* H = (unsigned short*)((char*)d_ws + 65792); // 4096*4096 bf16 = 32 MB

    hipMemsetAsync(counts, 0, NE * sizeof(int), stream);
    hipMemsetAsync(d_out, 0, (size_t)out_size * sizeof(float), stream);

    gate_kernel<<<T_TOKENS / 4, 256, 0, stream>>>(x, Wg, bg, counts, topk);
    scatter_kernel<<<1, 256, 0, stream>>>(counts, topk, offsets, list);

    for (int e = 0; e < NE; e++) {
        gemm1_kernel<<<dim3(T_TOKENS / 64, DF / 64), 256, 0, stream>>>(
            x, W1, b1, counts, offsets, list, H, e);
        gemm2_kernel<<<dim3(T_TOKENS / 64, DM / 64), 256, 0, stream>>>(
            H, W2, b2, counts, offsets, list, out, e);
    }
}

// Round 2
// 685.228 us; speedup vs baseline: 3.9328x; 3.9328x over previous
//
#include <hip/hip_runtime.h>
#include <hip/hip_bf16.h>

#define T_TOKENS 4096
#define DM 1024
#define DF 4096
#define NE 8
#define MAXROWS 9216   // 8192 + 8*128 padding

typedef float f32x4 __attribute__((ext_vector_type(4)));
typedef short bf16x8 __attribute__((ext_vector_type(8)));

__device__ __forceinline__ unsigned short f2bf(float f) {
    union { float f; unsigned int u; } v; v.f = f;
    unsigned int r = v.u + 0x7fffu + ((v.u >> 16) & 1u);
    return (unsigned short)(r >> 16);
}

// async global->LDS, 16B per lane; LDS dest = wave-uniform base + lane*16
__device__ __forceinline__ void g2l16(const void* g, void* l) {
    __builtin_amdgcn_global_load_lds(
        (const __attribute__((address_space(1))) void*)g,
        (__attribute__((address_space(3))) void*)l, 16, 0, 0);
}

// ---------------- gating: logits -> top2 (softmax monotone, skip it) ----------------
__global__ __launch_bounds__(256) void gate_kernel(
    const float* __restrict__ x, const float* __restrict__ Wg, const float* __restrict__ bg,
    int* __restrict__ counts, int* __restrict__ topk)
{
    int wave = threadIdx.x >> 6;
    int lane = threadIdx.x & 63;
    int t = blockIdx.x * 4 + wave;
    float acc[NE];
#pragma unroll
    for (int e = 0; e < NE; e++) acc[e] = 0.f;
    const float* xr = x + (size_t)t * DM;
#pragma unroll
    for (int i = 0; i < DM / 64; i++) {
        int d = lane + i * 64;
        float xv = xr[d];
        const float4* wg = (const float4*)(Wg + d * NE);
        float4 w0 = wg[0], w1 = wg[1];
        acc[0] += xv * w0.x; acc[1] += xv * w0.y; acc[2] += xv * w0.z; acc[3] += xv * w0.w;
        acc[4] += xv * w1.x; acc[5] += xv * w1.y; acc[6] += xv * w1.z; acc[7] += xv * w1.w;
    }
#pragma unroll
    for (int e = 0; e < NE; e++) {
#pragma unroll
        for (int off = 32; off > 0; off >>= 1)
            acc[e] += __shfl_down(acc[e], off);
    }
    if (lane == 0) {
        float lg[NE];
#pragma unroll
        for (int e = 0; e < NE; e++) lg[e] = acc[e] + bg[e];
        int b1i = 0; float b1v = lg[0];
        for (int e = 1; e < NE; e++) if (lg[e] > b1v) { b1v = lg[e]; b1i = e; }
        int b2i = -1; float b2v = -1e30f;
        for (int e = 0; e < NE; e++) {
            if (e == b1i) continue;
            if (b2i < 0 || lg[e] > b2v) { b2v = lg[e]; b2i = e; }
        }
        topk[t * 2 + 0] = b1i;
        topk[t * 2 + 1] = b2i;
        atomicAdd(&counts[b1i], 1);
        atomicAdd(&counts[b2i], 1);
    }
}

// ---------------- per-expert token lists, segments padded to 128 rows ----------------
__global__ __launch_bounds__(256) void scatter_kernel(
    const int* __restrict__ counts, const int* __restrict__ topk,
    int* __restrict__ offsets, int* __restrict__ list)
{
    __shared__ int offs[NE + 1];
    __shared__ int cur[NE];
    if (threadIdx.x == 0) {
        int s = 0;
        for (int e = 0; e < NE; e++) {
            offs[e] = s; offsets[e] = s;
            s += (counts[e] + 127) & ~127;
        }
        offs[NE] = s; offsets[NE] = s;
    }
    if (threadIdx.x < NE) cur[threadIdx.x] = 0;
    __syncthreads();
    for (int i = threadIdx.x; i < T_TOKENS * 2; i += 256) {
        int e = topk[i];
        int pos = atomicAdd(&cur[e], 1);
        list[offs[e] + pos] = i >> 1;
    }
    __syncthreads();
    for (int e = 0; e < NE; e++) {
        int s = offs[e] + counts[e];
        int t = offs[e + 1];
        for (int i = s + threadIdx.x; i < t; i += 256) list[i] = -1;
    }
}

// ---------------- x fp32 -> bf16 ----------------
__global__ __launch_bounds__(256) void cvt_x_kernel(
    const float* __restrict__ x, unsigned short* __restrict__ xb)
{
    int i = (blockIdx.x * 256 + threadIdx.x) * 4;
    float4 v = *(const float4*)(x + i);
    unsigned short o[4] = { f2bf(v.x), f2bf(v.y), f2bf(v.z), f2bf(v.w) };
    *(uint2*)(xb + i) = *(const uint2*)o;
}

// ---------------- W [e][K][N] fp32 -> [e][N][K] bf16 (tile transpose via LDS) ------
__global__ __launch_bounds__(256) void tr_cvt_kernel(
    const float* __restrict__ src, unsigned short* __restrict__ dst, int K, int N)
{
    const int e = blockIdx.z;
    src += (size_t)e * K * N;
    dst += (size_t)e * N * K;
    const int n0 = blockIdx.x * 64, k0 = blockIdx.y * 64;
    __shared__ unsigned short tile[64][68];
    const int t = threadIdx.x;
    const int tx = t & 63, ty = t >> 6;
#pragma unroll
    for (int r = 0; r < 16; r++) {
        int k = ty * 16 + r;
        tile[tx][k] = f2bf(src[(size_t)(k0 + k) * N + n0 + tx]);
    }
    __syncthreads();
    const int kx = (t & 15) * 4, ny = t >> 4;
#pragma unroll
    for (int r = 0; r < 4; r++) {
        int n = ny + r * 16;
        *(uint2*)(dst + (size_t)(n0 + n) * K + k0 + kx) = *(const uint2*)&tile[n][kx];
    }
}

// ---------------- GEMM1: H = relu(gather(xb) @ W1T^T + b1), all experts fused ------
__global__ __launch_bounds__(256) void gemm1_kernel(
    const unsigned short* __restrict__ xb, const unsigned short* __restrict__ W1T,
    const float* __restrict__ b1, const int* __restrict__ offsets,
    const int* __restrict__ list, unsigned short* __restrict__ H)
{
    const int total = offsets[NE];
    const int row0 = blockIdx.x * 128;
    if (row0 >= total) return;
    int e = 0;
    while (row0 >= offsets[e + 1]) e++;
    const int n0 = blockIdx.y * 128;

    __shared__ unsigned short Asm[128 * 32];
    __shared__ unsigned short Bsm[128 * 32];

    const int tid = threadIdx.x;
    const int w = tid >> 6, lane = tid & 63;
    const int quad = lane >> 4, l16 = lane & 15;
    const int wm = w >> 1, wn = w & 1;

    const int sr = lane >> 2;        // row within 16-row chunk
    const int sc = (lane & 3) * 8;   // k offset (8 bf16 = 16B)
    const int ra1 = 32 * w + sr, ra2 = ra1 + 16;
    int t1 = list[row0 + ra1]; if (t1 < 0) t1 = 0;
    int t2 = list[row0 + ra2]; if (t2 < 0) t2 = 0;
    const unsigned short* gA1 = xb + (size_t)t1 * DM + sc;
    const unsigned short* gA2 = xb + (size_t)t2 * DM + sc;
    const unsigned short* Wb = W1T + (size_t)e * DF * DM;
    const unsigned short* gB1 = Wb + (size_t)(n0 + 32 * w + sr) * DM + sc;
    const unsigned short* gB2 = gB1 + (size_t)16 * DM;
    unsigned short* lA1 = Asm + (2 * w) * 512;
    unsigned short* lA2 = Asm + (2 * w + 1) * 512;
    unsigned short* lB1 = Bsm + (2 * w) * 512;
    unsigned short* lB2 = Bsm + (2 * w + 1) * 512;

    f32x4 acc[4][4];
#pragma unroll
    for (int i = 0; i < 4; i++)
#pragma unroll
        for (int j = 0; j < 4; j++) acc[i][j] = (f32x4){0.f, 0.f, 0.f, 0.f};

    for (int kk = 0; kk < DM; kk += 32) {
        g2l16(gA1 + kk, lA1);
        g2l16(gA2 + kk, lA2);
        g2l16(gB1 + kk, lB1);
        g2l16(gB2 + kk, lB2);
        __syncthreads();
        bf16x8 af[4];
#pragma unroll
        for (int i = 0; i < 4; i++)
            af[i] = *(const bf16x8*)&Asm[(wm * 64 + i * 16 + l16) * 32 + quad * 8];
#pragma unroll
        for (int j = 0; j < 4; j++) {
            bf16x8 bf = *(const bf16x8*)&Bsm[(wn * 64 + j * 16 + l16) * 32 + quad * 8];
#pragma unroll
            for (int i = 0; i < 4; i++)
                acc[i][j] = __builtin_amdgcn_mfma_f32_16x16x32_bf16(af[i], bf, acc[i][j], 0, 0, 0);
        }
        __syncthreads();
    }

    const float* bias = b1 + e * DF;
#pragma unroll
    for (int j = 0; j < 4; j++) {
        int n = n0 + wn * 64 + j * 16 + l16;
        float bj = bias[n];
#pragma unroll
        for (int i = 0; i < 4; i++) {
            int row = row0 + wm * 64 + i * 16 + quad * 4;
#pragma unroll
            for (int r = 0; r < 4; r++) {
                float v = acc[i][j][r] + bj;
                v = fmaxf(v, 0.f);
                H[(size_t)(row + r) * DF + n] = f2bf(v);
            }
        }
    }
}

// ---------------- GEMM2: out[tok] += H @ W2T^T + b2, all experts fused -------------
__global__ __launch_bounds__(256) void gemm2_kernel(
    const unsigned short* __restrict__ H, const unsigned short* __restrict__ W2T,
    const float* __restrict__ b2, const int* __restrict__ offsets,
    const int* __restrict__ list, float* __restrict__ out)
{
    const int total = offsets[NE];
    const int row0 = blockIdx.x * 128;
    if (row0 >= total) return;
    int e = 0;
    while (row0 >= offsets[e + 1]) e++;
    const int n0 = blockIdx.y * 128;

    __shared__ unsigned short Asm[128 * 32];
    __shared__ unsigned short Bsm[128 * 32];

    const int tid = threadIdx.x;
    const int w = tid >> 6, lane = tid & 63;
    const int quad = lane >> 4, l16 = lane & 15;
    const int wm = w >> 1, wn = w & 1;

    const int sr = lane >> 2;
    const int sc = (lane & 3) * 8;
    const unsigned short* gA1 = H + (size_t)(row0 + 32 * w + sr) * DF + sc;
    const unsigned short* gA2 = gA1 + (size_t)16 * DF;
    const unsigned short* Wb = W2T + (size_t)e * DM * DF;
    const unsigned short* gB1 = Wb + (size_t)(n0 + 32 * w + sr) * DF + sc;
    const unsigned short* gB2 = gB1 + (size_t)16 * DF;
    unsigned short* lA1 = Asm + (2 * w) * 512;
    unsigned short* lA2 = Asm + (2 * w + 1) * 512;
    unsigned short* lB1 = Bsm + (2 * w) * 512;
    unsigned short* lB2 = Bsm + (2 * w + 1) * 512;

    f32x4 acc[4][4];
#pragma unroll
    for (int i = 0; i < 4; i++)
#pragma unroll
        for (int j = 0; j < 4; j++) acc[i][j] = (f32x4){0.f, 0.f, 0.f, 0.f};

    for (int kk = 0; kk < DF; kk += 32) {
        g2l16(gA1 + kk, lA1);
        g2l16(gA2 + kk, lA2);
        g2l16(gB1 + kk, lB1);
        g2l16(gB2 + kk, lB2);
        __syncthreads();
        bf16x8 af[4];
#pragma unroll
        for (int i = 0; i < 4; i++)
            af[i] = *(const bf16x8*)&Asm[(wm * 64 + i * 16 + l16) * 32 + quad * 8];
#pragma unroll
        for (int j = 0; j < 4; j++) {
            bf16x8 bf = *(const bf16x8*)&Bsm[(wn * 64 + j * 16 + l16) * 32 + quad * 8];
#pragma unroll
            for (int i = 0; i < 4; i++)
                acc[i][j] = __builtin_amdgcn_mfma_f32_16x16x32_bf16(af[i], bf, acc[i][j], 0, 0, 0);
        }
        __syncthreads();
    }

    const float* bias = b2 + e * DM;
#pragma unroll
    for (int j = 0; j < 4; j++) {
        int n = n0 + wn * 64 + j * 16 + l16;
        float bj = bias[n];
#pragma unroll
        for (int i = 0; i < 4; i++) {
            int row = row0 + wm * 64 + i * 16 + quad * 4;
#pragma unroll
            for (int r = 0; r < 4; r++) {
                int tk = list[row + r];
                if (tk >= 0)
                    atomicAdd(&out[(size_t)tk * DM + n], acc[i][j][r] + bj);
            }
        }
    }
}

extern "C" void kernel_launch(void* const* d_in, const int* in_sizes, int n_in,
                              void* d_out, int out_size, void* d_ws, size_t ws_size,
                              hipStream_t stream)
{
    const float* x  = (const float*)d_in[0];
    const float* Wg = (const float*)d_in[1];
    const float* bg = (const float*)d_in[2];
    const float* W1 = (const float*)d_in[3];
    const float* b1 = (const float*)d_in[4];
    const float* W2 = (const float*)d_in[5];
    const float* b2 = (const float*)d_in[6];
    float* out = (float*)d_out;

    char* ws = (char*)d_ws;
    int* counts  = (int*)(ws + 0);            // 8 ints
    int* offsets = (int*)(ws + 64);           // 9 ints
    int* topk    = (int*)(ws + 256);          // 8192 ints
    int* list    = (int*)(ws + 33024);        // 9216 ints
    unsigned short* xb = (unsigned short*)(ws + (1u << 20));           // 8 MB
    unsigned short* WT = (unsigned short*)(ws + (16u << 20));          // 64 MB (W1T then W2T)
    unsigned short* Hb = (unsigned short*)(ws + (80u << 20));          // 75.5 MB

    hipMemsetAsync(counts, 0, NE * sizeof(int), stream);
    hipMemsetAsync(d_out, 0, (size_t)out_size * sizeof(float), stream);

    gate_kernel<<<T_TOKENS / 4, 256, 0, stream>>>(x, Wg, bg, counts, topk);
    scatter_kernel<<<1, 256, 0, stream>>>(counts, topk, offsets, list);
    cvt_x_kernel<<<T_TOKENS * DM / 1024, 256, 0, stream>>>(x, xb);

    // W1: [e][K=DM][N=DF] -> [e][DF][DM]
    tr_cvt_kernel<<<dim3(DF / 64, DM / 64, NE), 256, 0, stream>>>(W1, WT, DM, DF);
    gemm1_kernel<<<dim3(MAXROWS / 128, DF / 128), 256, 0, stream>>>(
        xb, WT, b1, offsets, list, Hb);

    // W2: [e][K=DF][N=DM] -> [e][DM][DF]  (reuses WT buffer; stream serializes)
    tr_cvt_kernel<<<dim3(DM / 64, DF / 64, NE), 256, 0, stream>>>(W2, WT, DF, DM);
    gemm2_kernel<<<dim3(MAXROWS / 128, DM / 128), 256, 0, stream>>>(
        Hb, WT, b2, offsets, list, out);
}